// Round 7
// baseline (248.050 us; speedup 1.0000x reference)
//
#include <hip/hip_runtime.h>
#include <math.h>

typedef __attribute__((ext_vector_type(8))) short short8;
typedef __attribute__((ext_vector_type(4))) float float4v;

#define KDIM  512
#define NQKV  1536

__device__ __forceinline__ unsigned short f2bf(float f) {
    unsigned int u = __float_as_uint(f);
    u += 0x7FFFu + ((u >> 16) & 1u);   // round-to-nearest-even
    return (unsigned short)(u >> 16);
}
__device__ __forceinline__ float bf2f(unsigned short u) {
    return __uint_as_float(((unsigned int)u) << 16);
}

// async global->LDS DMA, 16 B per lane; LDS dest = wave-uniform base + lane*16
__device__ __forceinline__ void gl2lds16(const unsigned short* g, unsigned short* l) {
    __builtin_amdgcn_global_load_lds(
        (const __attribute__((address_space(1))) void*)g,
        (__attribute__((address_space(3))) void*)l, 16, 0, 0);
}

// ---------------- fused cast: x (with roll -32) + both weight matrices ----------
// blocks [0, 16384): x cast+roll ; blocks [16384, 17408): w_qkv / w_proj cast
__global__ __launch_bounds__(256) void cast_all_kernel(const float* __restrict__ x,
                                                       const float* __restrict__ wqkv,
                                                       const float* __restrict__ wproj,
                                                       unsigned short* __restrict__ xb,
                                                       unsigned short* __restrict__ wqkvb,
                                                       unsigned short* __restrict__ wprojb) {
    if (blockIdx.x < 16384) {
        int tid = blockIdx.x * 256 + threadIdx.x;
        int t = tid >> 7;               // token row 0..32767 (shifted order)
        int c = (tid & 127) << 2;
        int b = t >> 12, n = t & 4095;
        int src = (b << 12) | ((n + 32) & 4095);    // roll(x, -32)
        float4 v = *(const float4*)(x + (((size_t)src) << 9) + c);
        ushort4 o;
        o.x = f2bf(v.x); o.y = f2bf(v.y); o.z = f2bf(v.z); o.w = f2bf(v.w);
        *(ushort4*)(xb + (((size_t)t) << 9) + c) = o;
    } else {
        int tid = (blockIdx.x - 16384) * 256 + threadIdx.x;
        int e = tid << 2;
        if (e < NQKV * KDIM) {
            float4 v = *(const float4*)(wqkv + e);
            ushort4 o; o.x = f2bf(v.x); o.y = f2bf(v.y); o.z = f2bf(v.z); o.w = f2bf(v.w);
            *(ushort4*)(wqkvb + e) = o;
        } else {
            int e2 = e - NQKV * KDIM;
            float4 v = *(const float4*)(wproj + e2);
            ushort4 o; o.x = f2bf(v.x); o.y = f2bf(v.y); o.z = f2bf(v.z); o.w = f2bf(v.w);
            *(ushort4*)(wprojb + e2) = o;
        }
    }
}

// ---------------- QKV GEMM: C[M,N] = A[M,K] @ B[N,K]^T ----------------
// 128x128 tile, BK=64 (32 MFMA per barrier pair), 4 waves (2x2).
// Staging via global_load_lds width=16 into flat row-major stride-64 LDS with an
// XOR col-block swizzle (applied on the GLOBAL address side, since the DMA's LDS
// destination must be lane-contiguous): stored block p at row r holds source
// col-block p^(r&7). Fragment ds_read_b128 then hits 8 distinct bank groups.
// NOTE: reg-staged A (fused f32 cast) was tried and is a measured LOSS (103 vs
// 72 us): mixing reg-loads with DMA defeats the vmcnt scheduling (cf. m151).
// Partial software-pipelining of this structure is also a measured no-op
// (m99/m100/m131/m139) - only the full 8-phase template breaks the ceiling.
// XCD-aware bijective swizzle: nwg%8==0; blocks sharing an A-panel (same bm)
// land on the same XCD -> A fetched ~once from HBM (FETCH 135 -> ~30 MB).
template<int N>
__global__ __launch_bounds__(256, 2) void gemm_kernel(
        const unsigned short* __restrict__ A,
        const unsigned short* __restrict__ B,
        unsigned short* __restrict__ Cb) {
    __shared__ __align__(16) unsigned short As[128 * 64];
    __shared__ __align__(16) unsigned short Bs[128 * 64];
    constexpr int GX  = N / 128;         // blocks along n: 12 (QKV)
    constexpr int PER = (GX * 256) / 8;  // blocks per XCD (exact: nwg % 8 == 0)
    const int wgid = blockIdx.y * GX + blockIdx.x;          // dispatch-linear
    const int swz  = (wgid & 7) * PER + (wgid >> 3);        // bijective chunking
    const int bm = swz / GX;
    const int bn = swz % GX;

    const int tid = threadIdx.x;
    const int wave = tid >> 6, lane = tid & 63;
    const int quad = lane >> 4, l16 = lane & 15;
    const int wm = (wave >> 1) * 64, wn = (wave & 1) * 64;
    // DMA: chunk = 8 rows x 64 cols = 1 KB. Lane covers row chunk*8+(lane>>3),
    // stored col-block lane&7, which must hold source col-block (lane&7)^(row&7).
    const int srow = lane >> 3;                  // 0..7 within chunk
    const int scol = ((lane & 7) ^ srow) * 8;    // swizzled source column

    float4v acc[4][4] = {};

    const unsigned short* Abase = A + (size_t)(bm * 128) * KDIM;
    const unsigned short* Bbase = B + (size_t)(bn * 128) * KDIM;

    for (int k0 = 0; k0 < KDIM; k0 += 64) {
        #pragma unroll
        for (int j = 0; j < 4; j++) {
            int chunk = j * 4 + wave;               // 0..15
            int row = chunk * 8 + srow;             // 0..127
            gl2lds16(Abase + (size_t)row * KDIM + k0 + scol, As + chunk * 512);
            gl2lds16(Bbase + (size_t)row * KDIM + k0 + scol, Bs + chunk * 512);
        }
        __syncthreads();
        #pragma unroll
        for (int ki = 0; ki < 2; ki++) {
            short8 af[4], bf[4];
            #pragma unroll
            for (int mi = 0; mi < 4; mi++) {
                int r = wm + mi * 16 + l16;
                int blk = (ki * 4 + quad) ^ (l16 & 7);
                af[mi] = *(const short8*)(As + r * 64 + blk * 8);
            }
            #pragma unroll
            for (int ni = 0; ni < 4; ni++) {
                int r = wn + ni * 16 + l16;
                int blk = (ki * 4 + quad) ^ (l16 & 7);
                bf[ni] = *(const short8*)(Bs + r * 64 + blk * 8);
            }
            #pragma unroll
            for (int mi = 0; mi < 4; mi++)
                #pragma unroll
                for (int ni = 0; ni < 4; ni++)
                    acc[mi][ni] = __builtin_amdgcn_mfma_f32_16x16x32_bf16(
                        af[mi], bf[ni], acc[mi][ni], 0, 0, 0);
        }
        __syncthreads();
    }

    #pragma unroll
    for (int mi = 0; mi < 4; mi++) {
        #pragma unroll
        for (int r = 0; r < 4; r++) {
            int m = bm * 128 + wm + mi * 16 + quad * 4 + r;
            #pragma unroll
            for (int ni = 0; ni < 4; ni++) {
                int n = bn * 128 + wn + ni * 16 + l16;
                Cb[(size_t)m * N + n] = f2bf(acc[mi][ni][r]);
            }
        }
    }
}

// ---------------- fused attention + projection, one WINDOW per block ----------
// Phase 1 (attn): 512 threads = 64 tokens x 8 heads, 1 (token,head) pair per
// thread. S[h][g] = Q_h.K_g over heads per token, softmax (scale 0.125),
// O[h] = sum_g P[h][g] V[g]. K/V read from global: the 8 head-lanes of a token
// issue IDENTICAL addresses in the same instruction -> one L1 line fetch.
// Output written straight into a 64 KB LDS tile in the proj-input layout
// (row = h*8 + w/8, col = (w%8)*64 + d), with a per-row XOR swizzle on the
// 8-bf16 col-block index: key(r) = (r ^ (r>>3)) & 7. Write side: the 8 head
// lanes of a token hit 8 distinct bank groups (keys c^h distinct in h).
// Read side (A-fragments): 16 consecutive rows at one col-block -> keys form
// two full 0..7 permutations -> 2 lanes/bank = conflict-free.
// Phase 2 (proj GEMM): C[64x512] = Asf @ wprojb^T. 8 waves, each owns a
// 64-col strip (4 m-tiles x 4 n-tiles, acc = 64 f32/lane). B-fragments are
// read DIRECTLY from global (wprojb = 0.5 MB, L2-resident; ~0.5 MB/block,
// 256 MB aggregate at L2 bandwidth) -> no staging DMA, no barriers in the
// K-loop, compiler free to pipeline all 16 K-steps.
// Epilogue: + bias, roll(+32) on token rows, f32 store. Eliminates the aob
// round-trip (64 MB HBM) and one launch vs the split attn/proj kernels.
__global__ __launch_bounds__(512, 2) void attnproj_kernel(
        const unsigned short* __restrict__ qkvb,
        const unsigned short* __restrict__ wprojb,
        const float* __restrict__ bias,
        float* __restrict__ out) {
    __shared__ __align__(16) unsigned short Asf[64 * 512];   // 64 KB
    const int tid = threadIdx.x;
    const int win = blockIdx.x;          // 512 windows

    // ======================= phase 1: attention =======================
    {
        const int w = tid >> 3, h = tid & 7;
        const int t = win * 64 + w;
        const unsigned short* base = qkvb + (size_t)t * NQKV;

        float s[8];
        {
            short8 qs[8];
            #pragma unroll
            for (int dc = 0; dc < 8; dc++)
                qs[dc] = *(const short8*)(base + h * 64 + dc * 8);
            float qv[64];
            #pragma unroll
            for (int dc = 0; dc < 8; dc++)
                #pragma unroll
                for (int j = 0; j < 8; j++)
                    qv[dc * 8 + j] = bf2f((unsigned short)qs[dc][j]);
            #pragma unroll
            for (int g = 0; g < 8; g++) {
                const unsigned short* krow = base + 512 + g * 64;
                float acc = 0.f;
                #pragma unroll
                for (int dc = 0; dc < 8; dc++) {
                    short8 ks = *(const short8*)(krow + dc * 8);
                    #pragma unroll
                    for (int j = 0; j < 8; j++)
                        acc += qv[dc * 8 + j] * bf2f((unsigned short)ks[j]);
                }
                s[g] = acc;
            }
        }

        float mx = s[0];
        #pragma unroll
        for (int g = 1; g < 8; g++) mx = fmaxf(mx, s[g]);
        float p[8], sum = 0.f;
        #pragma unroll
        for (int g = 0; g < 8; g++) { p[g] = __expf((s[g] - mx) * 0.125f); sum += p[g]; }
        float inv = 1.f / sum;
        #pragma unroll
        for (int g = 0; g < 8; g++) p[g] *= inv;

        float o[64];
        #pragma unroll
        for (int j = 0; j < 64; j++) o[j] = 0.f;
        #pragma unroll
        for (int g = 0; g < 8; g++) {
            const unsigned short* vrow = base + 1024 + g * 64;
            #pragma unroll
            for (int dc = 0; dc < 8; dc++) {
                short8 vs = *(const short8*)(vrow + dc * 8);
                #pragma unroll
                for (int j = 0; j < 8; j++)
                    o[dc * 8 + j] += p[g] * bf2f((unsigned short)vs[j]);
            }
        }

        // write to LDS in proj-input layout, swizzled
        int lw = h * 8 + (w >> 3);                  // local proj row 0..63
        int keyr = (lw ^ (lw >> 3)) & 7;
        unsigned short* dstrow = Asf + lw * 512;
        #pragma unroll
        for (int dc = 0; dc < 8; dc++) {
            short8 pk;
            #pragma unroll
            for (int j = 0; j < 8; j++) pk[j] = (short)f2bf(o[dc * 8 + j]);
            int cb = (w & 7) * 8 + dc;              // logical col-block 0..63
            *(short8*)(dstrow + ((cb ^ keyr) * 8)) = pk;
        }
    }
    __syncthreads();

    // ======================= phase 2: projection GEMM =======================
    const int wave = tid >> 6, lane = tid & 63;
    const int quad = lane >> 4, l16 = lane & 15;
    const int wc = wave;                            // cols [wc*64, wc*64+64)

    float4v acc[4][4] = {};
    #pragma unroll
    for (int ks = 0; ks < 16; ks++) {               // BK = 32 per MFMA K
        short8 af[4], bfr[4];
        #pragma unroll
        for (int mi = 0; mi < 4; mi++) {
            int r = mi * 16 + l16;                  // A row 0..63
            int kb = ks * 4 + quad;                 // logical k-block 0..63
            af[mi] = *(const short8*)(Asf + r * 512 + ((kb ^ ((r ^ (r >> 3)) & 7)) * 8));
        }
        #pragma unroll
        for (int ni = 0; ni < 4; ni++) {
            int r = wc * 64 + ni * 16 + l16;        // B (n) row
            bfr[ni] = *(const short8*)(wprojb + (size_t)r * KDIM + ks * 32 + quad * 8);
        }
        #pragma unroll
        for (int mi = 0; mi < 4; mi++)
            #pragma unroll
            for (int ni = 0; ni < 4; ni++)
                acc[mi][ni] = __builtin_amdgcn_mfma_f32_16x16x32_bf16(
                    af[mi], bfr[ni], acc[mi][ni], 0, 0, 0);
    }

    // epilogue: bias + roll(+32) + f32 store
    #pragma unroll
    for (int mi = 0; mi < 4; mi++) {
        #pragma unroll
        for (int r4 = 0; r4 < 4; r4++) {
            int m = win * 64 + mi * 16 + quad * 4 + r4;
            int b = m >> 12, pp = m & 4095;
            int nrow = (pp + 32) & 4095;            // roll(out, +32)
            float* orow = out + (((size_t)((b << 12) | nrow)) << 9);
            #pragma unroll
            for (int ni = 0; ni < 4; ni++) {
                int n = wc * 64 + ni * 16 + l16;
                orow[n] = acc[mi][ni][r4] + bias[n];
            }
        }
    }
}

extern "C" void kernel_launch(void* const* d_in, const int* in_sizes, int n_in,
                              void* d_out, int out_size, void* d_ws, size_t ws_size,
                              hipStream_t stream) {
    const float* x      = (const float*)d_in[0];
    const float* w_qkv  = (const float*)d_in[1];
    const float* w_proj = (const float*)d_in[2];
    const float* b_proj = (const float*)d_in[3];
    float* out = (float*)d_out;

    char* ws = (char*)d_ws;
    unsigned short* xb     = (unsigned short*)(ws);                 // 32 MB
    unsigned short* wqkvb  = (unsigned short*)(ws + 33554432);      // 1.5 MB
    unsigned short* wprojb = (unsigned short*)(ws + 35127296);      // 0.5 MB
    unsigned short* qkvb   = (unsigned short*)(ws + 35651584);      // 96 MB

    cast_all_kernel<<<17408, 256, 0, stream>>>(x, w_qkv, w_proj, xb, wqkvb, wprojb);
    gemm_kernel<NQKV><<<dim3(12, 256), 256, 0, stream>>>(xb, wqkvb, qkvb);
    attnproj_kernel<<<512, 512, 0, stream>>>(qkvb, wprojb, b_proj, out);
}